// Round 3
// baseline (274.272 us; speedup 1.0000x reference)
//
#include <hip/hip_runtime.h>
#include <hip/hip_bf16.h>
#include <stdint.h>

// Problem constants (fixed shape): B=16, L=65536, H=64, K=64
#define LCOUNT 65536
#define LOUT   65473   // L - (H-1)
#define KF     64
#define HH     64
#define TL     1024    // output positions per block
#define ROW4   1104    // rep row stride in shorts; 1104/2 % 32 == 8 -> rows stagger bank groups
#define BSTR   68      // bounce row stride in floats; 68 % 32 == 4, rows 272B (16B-aligned)

typedef __attribute__((ext_vector_type(8))) short  short8;   // 8 bf16 (4 VGPRs)
typedef __attribute__((ext_vector_type(4))) short  short4v;  // 4 bf16 (2 VGPRs, 8B align)
typedef __attribute__((ext_vector_type(4))) float  float4v;  // 4 fp32
typedef __attribute__((ext_vector_type(2))) float  float2v;  // 2 fp32

__device__ __forceinline__ unsigned short f2bf(float f) {
    union { float f; uint32_t u; } c; c.f = f;
    uint32_t u = c.u;
    u += 0x7FFFu + ((u >> 16) & 1u);   // round-to-nearest-even
    return (unsigned short)(u >> 16);
}

__global__ __launch_bounds__(256, 4)
void hankel_kernel(const float* __restrict__ x,
                   const float* __restrict__ W,
                   const float* __restrict__ bias,
                   float* __restrict__ out)
{
    // LDS: 4352 + 8832 + 8192 + 256 + 256 + 17408 = 39296 B -> 4 blocks/CU (<= 40960)
    __shared__ __align__(16) float          xs_f[TL + 64];
    __shared__ __align__(16) unsigned short rep4[4 * ROW4];    // rep4[s][i] = bf16(x[blk + i + s])
    __shared__ __align__(16) float          muinv_s[2 * TL];   // interleaved {mu, inv}
    __shared__ float wsum_s[KF];
    __shared__ float bias_s[KF];
    __shared__ __align__(16) float          bounce[4][16 * BSTR];  // per-wave store staging

    const int tid  = threadIdx.x;
    const int lane = tid & 63;
    const int wv   = tid >> 6;
    const int m    = lane & 15;   // A-row (filter sub-idx) AND C/D col (position)
    const int quad = lane >> 4;

    const int tile     = blockIdx.x;
    const int bb       = blockIdx.y;
    const int block_lo = tile * TL;

    // ---- Phase A: stage x tile (float4 loads): fp32 for stats + packed bf16 row 0 ----
    {
        const float4v* xrow4 = (const float4v*)(x + (size_t)bb * LCOUNT);
        const int base4 = block_lo >> 2;           // block_lo % 4 == 0
        const int nf4   = (TL + 64) / 4;           // 272
        for (int i4 = tid; i4 < nf4; i4 += 256) {
            int g4 = base4 + i4;
            if (g4 > LCOUNT / 4 - 1) g4 = LCOUNT / 4 - 1;  // tail clamp; masked at store
            float4v v = xrow4[g4];
            *(float4v*)(xs_f + 4 * i4) = v;
            uint32_t plo = (uint32_t)f2bf(v[0]) | ((uint32_t)f2bf(v[1]) << 16);
            uint32_t phi = (uint32_t)f2bf(v[2]) | ((uint32_t)f2bf(v[3]) << 16);
            *(uint2*)(rep4 + 4 * i4) = make_uint2(plo, phi);   // row 0 (shift 0)
        }
    }

    // ---- Wsum[k] and bias -> LDS (threads 0..63; W is 16KB L1/L2-hot) ----
    if (tid < KF) {
        const float4v* wr = (const float4v*)(W + tid * HH);
        float s = 0.f;
        #pragma unroll
        for (int i = 0; i < HH / 4; ++i) {
            float4v w = wr[i];
            s += w[0] + w[1] + w[2] + w[3];
        }
        wsum_s[tid] = s;
        bias_s[tid] = bias[tid];
    }

    // ---- A fragments (W): afrag[t][ki] -> A[m=lane&15][h=quad*8+j+32*ki], filter k=t*16+m ----
    short8 afrag[4][2];
    #pragma unroll
    for (int t = 0; t < 4; ++t) {
        const int k = t * 16 + m;
        #pragma unroll
        for (int ki = 0; ki < 2; ++ki) {
            const float4v* wp = (const float4v*)(W + k * HH + quad * 8 + ki * 32);
            float4v w0 = wp[0];
            float4v w1 = wp[1];
            short8 f;
            f[0] = (short)f2bf(w0[0]); f[1] = (short)f2bf(w0[1]);
            f[2] = (short)f2bf(w0[2]); f[3] = (short)f2bf(w0[3]);
            f[4] = (short)f2bf(w1[0]); f[5] = (short)f2bf(w1[1]);
            f[6] = (short)f2bf(w1[2]); f[7] = (short)f2bf(w1[3]);
            afrag[t][ki] = f;
        }
    }

    __syncthreads();

    // ---- Phase B1: window stats: thread owns 4 consecutive positions p0 = 4*tid .. +3 ----
    {
        const int p0 = 4 * tid;
        const float4v* xv = (const float4v*)(xs_f + p0);   // 16B aligned
        float s1 = 0.f, s2 = 0.f;
        float4v v0 = xv[0];
        float4v v16 = xv[16];
        #pragma unroll
        for (int i = 0; i < 16; ++i) {
            float4v v = xv[i];
            s1 += v[0] + v[1] + v[2] + v[3];
            s2 += v[0] * v[0] + v[1] * v[1] + v[2] * v[2] + v[3] * v[3];
        }
        float mu4[4], inv4[4];
        #pragma unroll
        for (int i = 0; i < 4; ++i) {
            if (i > 0) {
                float xo = v0[i - 1], xn = v16[i - 1];   // slide window by 1
                s1 += xn - xo;
                s2 += xn * xn - xo * xo;
            }
            float mu  = s1 * (1.f / 64.f);
            float var = (s2 - 64.f * mu * mu) * (1.f / 63.f);
            var = var < 0.f ? 0.f : var;
            mu4[i]  = mu;
            inv4[i] = 1.f / (sqrtf(var) + 1e-6f);
        }
        float4v lo4, hi4;
        lo4[0] = mu4[0]; lo4[1] = inv4[0]; lo4[2] = mu4[1]; lo4[3] = inv4[1];
        hi4[0] = mu4[2]; hi4[1] = inv4[2]; hi4[2] = mu4[3]; hi4[3] = inv4[3];
        *(float4v*)(muinv_s + 8 * tid)     = lo4;   // byte 32*tid -> 16B aligned
        *(float4v*)(muinv_s + 8 * tid + 4) = hi4;
    }

    // ---- Phase B2: build shifted bf16 rows 1..3 from row 0 ----
    // rep4[s][8c..8c+7] = row0[8c+s .. 8c+s+7]; 136 chunks x 3 shifts (s=0 skipped)
    for (int tt = tid; tt < 544; tt += 256) {
        const int s = tt & 3;
        const int c = tt >> 2;          // 0..135
        if (s) {
            const int i0 = 8 * c + s;   // i0+7 <= 1090 < ROW4 (junk beyond 1087 never read)
            short8 w;
            #pragma unroll
            for (int j = 0; j < 8; ++j) w[j] = (short)rep4[i0 + j];
            *(short8*)(rep4 + s * ROW4 + 8 * c) = w;   // byte s*2208 + 16c -> 16B aligned
        }
    }
    __syncthreads();

    // ---- Phase C: MFMA + coalesced-store phase ----
    // B[k=quad*8+j][n=m] = x[p0 + m + quad*8 + j (+32ki)]
    //   = rep4[m&3][ p0 + (m&12) + quad*8 (+32ki) + j ]   -- base ≡ 0 mod 4 shorts (8B aligned)
    const unsigned short* myrow = rep4 + (m & 3) * ROW4 + (m & 12) + quad * 8;
    float* const bw   = &bounce[wv][0];
    float* const outb = out + (size_t)bb * LOUT * KF;
    const int kh     = 4 * (lane & 15);   // store k-offset
    const int prow   = lane >> 4;         // store position sub-row

    for (int g = wv; g < TL / 16; g += 4) {
        const int p0 = g * 16;

        // b64 reads, bank-verified conflict-free (row stagger 8 words + (m&12)/2 + 4q uniform)
        short4v a0 = *(const short4v*)(myrow + p0);
        short4v a1 = *(const short4v*)(myrow + p0 + 4);
        short4v a2 = *(const short4v*)(myrow + p0 + 32);
        short4v a3 = *(const short4v*)(myrow + p0 + 36);
        short8 b0 = __builtin_shufflevector(a0, a1, 0, 1, 2, 3, 4, 5, 6, 7);
        short8 b1 = __builtin_shufflevector(a2, a3, 0, 1, 2, 3, 4, 5, 6, 7);

        float2v mi = *(const float2v*)(muinv_s + 2 * (p0 + m));  // 4-lane broadcast, no conflict
        const float invv = mi[1];
        const float nmi  = -mi[0] * invv;   // -mu*inv

        float4v acc[4];
        #pragma unroll
        for (int t = 0; t < 4; ++t) acc[t] = (float4v){0.f, 0.f, 0.f, 0.f};

        #pragma unroll
        for (int t = 0; t < 4; ++t) {
            acc[t] = __builtin_amdgcn_mfma_f32_16x16x32_bf16(afrag[t][0], b0, acc[t], 0, 0, 0);
            acc[t] = __builtin_amdgcn_mfma_f32_16x16x32_bf16(afrag[t][1], b1, acc[t], 0, 0, 0);
        }

        // ---- epilogue: fold layernorm+bias+relu -> full-width bounce -> contiguous stores ----
        #pragma unroll
        for (int t = 0; t < 4; ++t) {
            // conflict-free broadcast reads (addr depends on t,quad only)
            float4v ws = *(const float4v*)(wsum_s + t * 16 + quad * 4);
            float4v bs = *(const float4v*)(bias_s + t * 16 + quad * 4);
            float4v v;
            #pragma unroll
            for (int r = 0; r < 4; ++r) {
                float vv = fmaf(acc[t][r], invv, fmaf(nmi, ws[r], bs[r]));
                v[r] = vv > 0.f ? vv : 0.f;
            }
            // write bank-group (m + 4t + quad) % 8 -> uniform, conflict-free b128
            *(float4v*)(bw + m * BSTR + t * 16 + quad * 4) = v;
        }
        asm volatile("s_waitcnt lgkmcnt(0)" ::: "memory");   // wave-private: no barrier needed
        #pragma unroll
        for (int s = 0; s < 4; ++s) {
            const int pos_in = 4 * s + prow;                 // 0..15
            // read bank-group (pos_in + (lane&15)) % 8 -> uniform, conflict-free b128
            float4v v = *(const float4v*)(bw + pos_in * BSTR + kh);
            const int pos = block_lo + p0 + pos_in;
            if (pos < LOUT) {
                // 4 complete 256B rows per instr = 1KB fully contiguous (fill-kernel shape)
                *(float4v*)(outb + (size_t)pos * KF + kh) = v;
            }
        }
        asm volatile("" ::: "memory");   // keep next iter's bounce writes after these reads
    }

    // ---- output 1: warmup scalar = 63 ----
    if (tile == 0 && bb == 0 && tid == 0) {
        out[(size_t)16 * LOUT * KF] = 63.0f;
    }
}

extern "C" void kernel_launch(void* const* d_in, const int* in_sizes, int n_in,
                              void* d_out, int out_size, void* d_ws, size_t ws_size,
                              hipStream_t stream) {
    const float* x = (const float*)d_in[0];   // (16, 65536) fp32
    const float* W = (const float*)d_in[1];   // (64, 64) fp32
    const float* b = (const float*)d_in[2];   // (64,) fp32
    float* out = (float*)d_out;               // 16*65473*64 fp32 + 1 (warmup)

    dim3 grid((LOUT + TL - 1) / TL, 16);      // 64 tiles x 16 batches
    hankel_kernel<<<grid, 256, 0, stream>>>(x, W, b, out);
}